// Round 10
// baseline (684.911 us; speedup 1.0000x reference)
//
#include <hip/hip_runtime.h>
#include <stdint.h>

#define S_LEN 8192
#define D_DIM 1024
#define SHIFT_W 256
#define NROWS 16384 /* B*S */

typedef __bf16 bf16;
typedef __bf16 bf16x8 __attribute__((ext_vector_type(8)));
typedef __bf16 bf16x4 __attribute__((ext_vector_type(4)));
typedef float f32x4 __attribute__((ext_vector_type(4)));

typedef __attribute__((address_space(1))) const void gas_t;
typedef __attribute__((address_space(3))) void las_t;

__device__ __forceinline__ void load_lds16(const void* g, void* l) {
  __builtin_amdgcn_global_load_lds((gas_t*)g, (las_t*)l, 16, 0, 0);
}

// bijective XCD remap (m204); nwg %8==0
__device__ __forceinline__ int xcd_swizzle(int orig, int nwg) {
  return (orig & 7) * (nwg >> 3) + (orig >> 3);
}

// ---------------- weight transpose + f32->bf16 ----------------
__global__ __launch_bounds__(256) void k_transpose_cvt(const float* __restrict__ in,
                                                       bf16* __restrict__ out,
                                                       int R, int C) {
  __shared__ float tile[32][33];
  int lx = threadIdx.x & 31, ly = threadIdx.x >> 5;
  int tc = blockIdx.x * 32, tr = blockIdx.y * 32;
#pragma unroll
  for (int i = 0; i < 4; i++)
    tile[ly + i * 8][lx] = in[(size_t)(tr + ly + i * 8) * C + tc + lx];
  __syncthreads();
#pragma unroll
  for (int i = 0; i < 4; i++)
    out[(size_t)(tc + ly + i * 8) * R + tr + lx] = (bf16)tile[lx][ly + i * 8];
}

// ---------------- rmsnorm (+optional roll) -> bf16 ----------------
__global__ __launch_bounds__(256) void k_rmsnorm(const float* __restrict__ x,
                                                 const float* __restrict__ g,
                                                 bf16* __restrict__ out, int shift) {
  int row = blockIdx.x;
  int b = row >> 13, r = row & (S_LEN - 1);
  int src = (b << 13) | ((r + shift) & (S_LEN - 1));
  int t = threadIdx.x;
  float4 v = *(const float4*)(x + (size_t)src * D_DIM + t * 4);
  float ss = v.x * v.x + v.y * v.y + v.z * v.z + v.w * v.w;
#pragma unroll
  for (int off = 32; off; off >>= 1) ss += __shfl_xor(ss, off);
  __shared__ float red[4];
  if ((t & 63) == 0) red[t >> 6] = ss;
  __syncthreads();
  ss = red[0] + red[1] + red[2] + red[3];
  float sc = rsqrtf(ss * (1.0f / D_DIM) + 1e-6f);
  float4 gv = *(const float4*)(g + t * 4);
  bf16x4 o;
  o[0] = (bf16)(v.x * gv.x * sc);
  o[1] = (bf16)(v.y * gv.y * sc);
  o[2] = (bf16)(v.z * gv.z * sc);
  o[3] = (bf16)(v.w * gv.w * sc);
  *(bf16x4*)(out + (size_t)row * D_DIM + t * 4) = o;
}

// ---------------- GEMM: C[M,N] = A[M,K] * BT[N,K]^T ----------------
// R10 = R9 with the B-read double-offset bug fixed (bBase already includes
// the 32768 B-region base; the read must NOT add it again).
// 256x128 tile, 4 waves (2M x 2N, wave-tile 128x64), BK=64,
// SINGLE 48KB LDS buffer => 2 blocks/CU — cross-block overlap hides the
// stage/drain stalls (m97/m114 mechanism). Simple 2-barrier K-step.
// LDS map: A [0,32768): kc*16384 + row*64 + chunk*16 (256 rows);
//          B [32768,49152): kc*8192 + row*64 + chunk*16 (128 rows).
// LDS chunk c holds global chunk c ^ ((row>>1)&3) (2-way-max bank pattern);
// achieved by pre-swizzling the per-lane GLOBAL source; dest wave-uniform.
// EPI: 0 = bf16 store; 1 = O-proj (roll -SHIFT + skip, f32); 2 = +bias gelu bf16;
//      3 = +bias +skip f32
template <int EPI>
__global__ __launch_bounds__(256, 2) void k_gemm(const bf16* __restrict__ A,
                                                 const bf16* __restrict__ BT,
                                                 bf16* __restrict__ obf,
                                                 float* __restrict__ of32,
                                                 const float* __restrict__ bias,
                                                 const float* __restrict__ skip,
                                                 int K, int ldc) {
  __shared__ __align__(16) char smem[49152];
  const int tid = threadIdx.x;
  const int wv = tid >> 6, lane = tid & 63;
  const int lr = lane & 15, lg = lane >> 4;
  const int wm = wv >> 1, wn = wv & 1;  // 2M x 2N waves

  // rect XCD map: grid = 64 * NB; XCD = bid&7 owns 16mb x (NB/2)nb rect
  const int NB = gridDim.x >> 6;
  const int xcd = blockIdx.x & 7;
  const int l = blockIdx.x >> 3;
  const int mb = ((xcd & 3) << 4) + (l & 15);
  const int nb = (xcd >> 2) * (NB >> 1) + (l >> 4);
  const int m0 = mb * 256, n0 = nb * 128;

  // staging source (per-lane, pre-swizzled): row r_local = tid>>2 (0..63),
  // lds-chunk c = tid&3 holds global chunk c ^ ((row>>1)&3).
  const int r_local = tid >> 2;
  const int c_src = ((tid & 3) ^ ((r_local >> 1) & 3)) * 8;  // elems
  const bf16* gA = A + (size_t)(m0 + r_local) * K + c_src;
  const bf16* gB = BT + (size_t)(n0 + r_local) * K + c_src;
  // staging dest base (WAVE-UNIFORM; HW adds lane*16)
  const int wvbase = wv * 1024;

  // read-side: chunk-XOR swizzle (lane-constant key)
  const int kchunk = (lg ^ ((lr >> 1) & 3)) << 4;
  const int aBase = wm * 8192 + lr * 64 + kchunk;          // + kc*16384 + mf*1024
  const int bBase = 32768 + wn * 4096 + lr * 64 + kchunk;  // + kc*8192 + nf*1024

  f32x4 acc[8][4] = {};

  for (int k0 = 0; k0 < K; k0 += 64) {
    __syncthreads();  // readers done with buffer
    // stage A: 2 kc planes x 4 row-groups (8 loads/wave)
#pragma unroll
    for (int kc = 0; kc < 2; kc++)
#pragma unroll
      for (int g = 0; g < 4; g++)
        load_lds16(gA + (size_t)(g * 64) * K + k0 + kc * 32,
                   smem + kc * 16384 + g * 4096 + wvbase);
    // stage B: 2 kc planes x 2 row-groups (4 loads/wave)
#pragma unroll
    for (int kc = 0; kc < 2; kc++)
#pragma unroll
      for (int g = 0; g < 2; g++)
        load_lds16(gB + (size_t)(g * 64) * K + k0 + kc * 32,
                   smem + 32768 + kc * 8192 + g * 4096 + wvbase);
    __syncthreads();  // vmcnt(0)+lgkm(0) drain + barrier: tile ready
#pragma unroll
    for (int kc = 0; kc < 2; kc++) {
      bf16x8 af[8], bfr[4];
#pragma unroll
      for (int mf = 0; mf < 8; mf++)
        af[mf] = *(const bf16x8*)(smem + kc * 16384 + aBase + mf * 1024);
#pragma unroll
      for (int nf = 0; nf < 4; nf++)
        bfr[nf] = *(const bf16x8*)(smem + kc * 8192 + bBase + nf * 1024);  // bBase has +32768
      __builtin_amdgcn_s_setprio(1);
#pragma unroll
      for (int mf = 0; mf < 8; mf++)
#pragma unroll
        for (int nf = 0; nf < 4; nf++)
          acc[mf][nf] = __builtin_amdgcn_mfma_f32_16x16x32_bf16(af[mf], bfr[nf], acc[mf][nf], 0, 0, 0);
      __builtin_amdgcn_s_setprio(0);
    }
  }

  // ---------------- epilogue: LDS transpose, vectorized I/O ----------------
  // 4 rounds (wmr, mh): the two waves with wm==wmr dump rows
  // [wmr*128 + mh*64, +64) x 128 cols into lds_f[64][132]; all 256 threads
  // read back 32 f32 and store vectorized.
  float* lds_f = (float*)smem;
  const int erow = tid >> 2;        // 0..63
  const int ecol0 = (tid & 3) * 4;  // 0,4,8,12
#pragma unroll
  for (int wmr = 0; wmr < 2; wmr++)
#pragma unroll
    for (int mh = 0; mh < 2; mh++) {
      __syncthreads();  // prior round's reads (or K-loop ds_reads) done
      if (wm == wmr) {
#pragma unroll
        for (int mf = 0; mf < 4; mf++) {
          int lrow = mf * 16 + lg * 4;
#pragma unroll
          for (int nf = 0; nf < 4; nf++) {
            int lcol = wn * 64 + nf * 16 + lr;
#pragma unroll
            for (int ii = 0; ii < 4; ii++)
              lds_f[(lrow + ii) * 132 + lcol] = acc[mh * 4 + mf][nf][ii];
          }
        }
      }
      __syncthreads();
      int gr = m0 + wmr * 128 + mh * 64 + erow;  // global row
      size_t orow;
      if constexpr (EPI == 1) {
        int b = gr >> 13, rr = gr & (S_LEN - 1);
        orow = (size_t)((b << 13) | ((rr - SHIFT_W) & (S_LEN - 1))) * ldc;
      } else {
        orow = (size_t)gr * ldc;
      }
#pragma unroll
      for (int j = 0; j < 8; j++) {
        f32x4 v = *(const f32x4*)&lds_f[erow * 132 + ecol0 + j * 16];
        int col = n0 + ecol0 + j * 16;
        if constexpr (EPI == 0) {
          bf16x4 o;
#pragma unroll
          for (int e = 0; e < 4; e++) o[e] = (bf16)v[e];
          *(bf16x4*)(obf + orow + col) = o;
        } else if constexpr (EPI == 1) {
          f32x4 s = *(const f32x4*)(skip + orow + col);
          f32x4 r = v + s;
          *(f32x4*)(of32 + orow + col) = r;
        } else if constexpr (EPI == 2) {
          f32x4 bi = *(const f32x4*)(bias + col);
          bf16x4 o;
#pragma unroll
          for (int e = 0; e < 4; e++) {
            float z = v[e] + bi[e];
            float u = 0.7978845608f * (z + 0.044715f * z * z * z);
            u = fminf(fmaxf(u, -15.f), 15.f);
            float ex = __expf(2.f * u);
            o[e] = (bf16)(0.5f * z * (1.f + (ex - 1.f) / (ex + 1.f)));
          }
          *(bf16x4*)(obf + orow + col) = o;
        } else {
          f32x4 bi = *(const f32x4*)(bias + col);
          f32x4 s = *(const f32x4*)(skip + orow + col);
          f32x4 r = v + bi + s;
          *(f32x4*)(of32 + orow + col) = r;
        }
      }
    }
}

// ---------------- windowed flash attention ----------------
__global__ __launch_bounds__(256) void k_attn(const bf16* __restrict__ qkv,
                                              bf16* __restrict__ out) {
  __shared__ __align__(16) char Qs[8192];
  __shared__ __align__(16) char Ks[8192];
  __shared__ __align__(16) char Vs[8192];
  __shared__ __align__(16) char Ps[4][2048];
  const int tid = threadIdx.x;
  const int wave = tid >> 6, lane = tid & 63;
  const int lr = lane & 15, lg = lane >> 4;
  const int bid = xcd_swizzle(blockIdx.x, gridDim.x);
  const int qt = bid & 7;
  const int h = (bid >> 3) & 15;
  const int bw = bid >> 7;
  const int rowbase = bw * 512;
  const int qrow0 = rowbase + qt * 64;

  {  // stage Q
    int r = tid >> 2, c0 = tid & 3;
    const bf16* src = qkv + (size_t)(qrow0 + r) * 3072 + h * 64;
#pragma unroll
    for (int j = 0; j < 2; j++) {
      int ch = c0 + j * 4;
      uint4 val = *(const uint4*)(src + ch * 8);
      int byte = (r * 128 + ch * 16) ^ ((r & 7) << 4);
      *(uint4*)(Qs + byte) = val;
    }
  }
  __syncthreads();
  bf16x8 qf[2];
  {
    int qr = wave * 16 + lr;
#pragma unroll
    for (int kk = 0; kk < 2; kk++) {
      int byte = (qr * 128 + (kk * 32 + lg * 8) * 2) ^ ((qr & 7) << 4);
      qf[kk] = *(const bf16x8*)(Qs + byte);
    }
  }

  f32x4 oacc[4] = {};
  float m_run = -__builtin_inff(), l_run = 0.f;

  for (int kt = 0; kt < 8; ++kt) {
    __syncthreads();
    {  // stage K and V^T
      int r = tid >> 2, c0 = tid & 3;
      const bf16* ksrc = qkv + (size_t)(rowbase + kt * 64 + r) * 3072 + 1024 + h * 64;
      const bf16* vsrc = ksrc + 1024;
#pragma unroll
      for (int j = 0; j < 2; j++) {
        int ch = c0 + j * 4;
        uint4 val = *(const uint4*)(ksrc + ch * 8);
        int byte = (r * 128 + ch * 16) ^ ((r & 7) << 4);
        *(uint4*)(Ks + byte) = val;
      }
#pragma unroll
      for (int j = 0; j < 2; j++) {
        int ch = c0 + j * 4;
        bf16x8 vv = *(const bf16x8*)(vsrc + ch * 8);
#pragma unroll
        for (int e = 0; e < 8; e++) {
          int d = ch * 8 + e;
          int byte = (d * 128 + r * 2) ^ ((d & 7) << 4);
          *(bf16*)(Vs + byte) = vv[e];
        }
      }
    }
    __syncthreads();
    f32x4 sc[4] = {};
#pragma unroll
    for (int kk = 0; kk < 2; kk++)
#pragma unroll
      for (int mf = 0; mf < 4; mf++) {
        int kr = mf * 16 + lr;
        int byte = (kr * 128 + (kk * 32 + lg * 8) * 2) ^ ((kr & 7) << 4);
        bf16x8 kf = *(const bf16x8*)(Ks + byte);
        sc[mf] = __builtin_amdgcn_mfma_f32_16x16x32_bf16(kf, qf[kk], sc[mf], 0, 0, 0);
      }
    float mx = -__builtin_inff();
#pragma unroll
    for (int mf = 0; mf < 4; mf++)
#pragma unroll
      for (int i = 0; i < 4; i++) mx = fmaxf(mx, sc[mf][i]);
    mx = fmaxf(mx, __shfl_xor(mx, 16));
    mx = fmaxf(mx, __shfl_xor(mx, 32));
    float mnew = fmaxf(m_run, mx);
    float alpha = __expf(0.125f * (m_run - mnew));
    float lsum = 0.f;
    float ps[4][4];
#pragma unroll
    for (int mf = 0; mf < 4; mf++)
#pragma unroll
      for (int i = 0; i < 4; i++) {
        float p = __expf(0.125f * (sc[mf][i] - mnew));
        ps[mf][i] = p;
        lsum += p;
      }
    lsum += __shfl_xor(lsum, 16);
    lsum += __shfl_xor(lsum, 32);
    l_run = l_run * alpha + lsum;
    m_run = mnew;
#pragma unroll
    for (int dm = 0; dm < 4; dm++) oacc[dm] *= alpha;
#pragma unroll
    for (int mf = 0; mf < 4; mf++) {
      bf16x4 pv;
#pragma unroll
      for (int i = 0; i < 4; i++) pv[i] = (bf16)ps[mf][i];
      int byte = (lr * 128 + (mf * 16 + lg * 4) * 2) ^ ((lr & 7) << 4);
      *(bf16x4*)(Ps[wave] + byte) = pv;
    }
#pragma unroll
    for (int kk = 0; kk < 2; kk++) {
      int pbyte = (lr * 128 + (kk * 32 + lg * 8) * 2) ^ ((lr & 7) << 4);
      bf16x8 pf = *(const bf16x8*)(Ps[wave] + pbyte);
#pragma unroll
      for (int dm = 0; dm < 4; dm++) {
        int d = dm * 16 + lr;
        int byte = (d * 128 + (kk * 32 + lg * 8) * 2) ^ ((d & 7) << 4);
        bf16x8 vf = *(const bf16x8*)(Vs + byte);
        oacc[dm] = __builtin_amdgcn_mfma_f32_16x16x32_bf16(vf, pf, oacc[dm], 0, 0, 0);
      }
    }
  }
  float inv = 1.f / l_run;
  int rowq = qrow0 + wave * 16 + lr;
#pragma unroll
  for (int dm = 0; dm < 4; dm++) {
    bf16x4 ov;
#pragma unroll
    for (int i = 0; i < 4; i++) ov[i] = (bf16)(oacc[dm][i] * inv);
    *(bf16x4*)(out + (size_t)rowq * 1024 + h * 64 + dm * 16 + lg * 4) = ov;
  }
}

// ---------------- launcher ----------------
extern "C" void kernel_launch(void* const* d_in, const int* in_sizes, int n_in,
                              void* d_out, int out_size, void* d_ws, size_t ws_size,
                              hipStream_t stream) {
  const float* x = (const float*)d_in[0];
  const float* wq = (const float*)d_in[1];
  const float* wk = (const float*)d_in[2];
  const float* wv = (const float*)d_in[3];
  const float* wo = (const float*)d_in[4];
  const float* ga = (const float*)d_in[5];
  const float* gf = (const float*)d_in[6];
  const float* w1 = (const float*)d_in[7];
  const float* b1 = (const float*)d_in[8];
  const float* w2 = (const float*)d_in[9];
  const float* b2 = (const float*)d_in[10];
  float* out = (float*)d_out;

  char* ws = (char*)d_ws;
  const size_t MB = 1024 * 1024;
  bf16* wqkvT = (bf16*)(ws);            // [3072][1024] bf16, 6MB
  bf16* woT = (bf16*)(ws + 6 * MB);     // [1024][1024], 2MB
  bf16* w1T = (bf16*)(ws + 8 * MB);     // [4096][1024], 8MB
  bf16* w2T = (bf16*)(ws + 16 * MB);    // [1024][4096], 8MB
  float* x1 = (float*)(ws + 24 * MB);   // [16384][1024] f32, 64MB
  bf16* hbuf = (bf16*)(ws + 88 * MB);   // 32MB: h -> attn_out -> h2
  bf16* qkv = (bf16*)(ws + 120 * MB);   // 96MB [16384][3072]; mid overlays
  bf16* mid = qkv;

  k_transpose_cvt<<<dim3(32, 32), 256, 0, stream>>>(wq, wqkvT, 1024, 1024);
  k_transpose_cvt<<<dim3(32, 32), 256, 0, stream>>>(wk, wqkvT + 1024 * 1024, 1024, 1024);
  k_transpose_cvt<<<dim3(32, 32), 256, 0, stream>>>(wv, wqkvT + 2 * 1024 * 1024, 1024, 1024);
  k_transpose_cvt<<<dim3(32, 32), 256, 0, stream>>>(wo, woT, 1024, 1024);
  k_transpose_cvt<<<dim3(128, 32), 256, 0, stream>>>(w1, w1T, 1024, 4096);
  k_transpose_cvt<<<dim3(32, 128), 256, 0, stream>>>(w2, w2T, 4096, 1024);

  // h = roll(rmsnorm(x, g_attn), -SHIFT)
  k_rmsnorm<<<NROWS, 256, 0, stream>>>(x, ga, hbuf, SHIFT_W);
  // qkv = h @ [wq|wk|wv]   (64 mb x 24 nb)
  k_gemm<0><<<64 * 24, 256, 0, stream>>>(hbuf, wqkvT, qkv, nullptr, nullptr, nullptr, 1024, 3072);
  // windowed attention
  k_attn<<<4096, 256, 0, stream>>>(qkv, hbuf);
  // x1 = roll(attn @ wo, -SHIFT) + x   (64 x 8)
  k_gemm<1><<<64 * 8, 256, 0, stream>>>(hbuf, woT, nullptr, x1, nullptr, x, 1024, 1024);
  // h2 = rmsnorm(x1, g_ff)
  k_rmsnorm<<<NROWS, 256, 0, stream>>>(x1, gf, hbuf, 0);
  // mid = gelu(h2 @ w1 + b1)   (64 x 32)
  k_gemm<2><<<64 * 32, 256, 0, stream>>>(hbuf, w1T, mid, nullptr, b1, nullptr, 1024, 4096);
  // out = mid @ w2 + b2 + x1   (64 x 8, K=4096)
  k_gemm<3><<<64 * 8, 256, 0, stream>>>(mid, w2T, nullptr, out, b2, x1, 4096, 1024);
}

// Round 11
// 637.859 us; speedup vs baseline: 1.0738x; 1.0738x over previous
//
#include <hip/hip_runtime.h>
#include <stdint.h>

#define S_LEN 8192
#define D_DIM 1024
#define SHIFT_W 256
#define NROWS 16384 /* B*S */

typedef __bf16 bf16;
typedef __bf16 bf16x8 __attribute__((ext_vector_type(8)));
typedef __bf16 bf16x4 __attribute__((ext_vector_type(4)));
typedef float f32x4 __attribute__((ext_vector_type(4)));

typedef __attribute__((address_space(1))) const void gas_t;
typedef __attribute__((address_space(3))) void las_t;

__device__ __forceinline__ void load_lds16(const void* g, void* l) {
  __builtin_amdgcn_global_load_lds((gas_t*)g, (las_t*)l, 16, 0, 0);
}

// bijective XCD remap (m204); nwg %8==0
__device__ __forceinline__ int xcd_swizzle(int orig, int nwg) {
  return (orig & 7) * (nwg >> 3) + (orig >> 3);
}

// ---------------- weight transpose + f32->bf16 ----------------
__global__ __launch_bounds__(256) void k_transpose_cvt(const float* __restrict__ in,
                                                       bf16* __restrict__ out,
                                                       int R, int C) {
  __shared__ float tile[32][33];
  int lx = threadIdx.x & 31, ly = threadIdx.x >> 5;
  int tc = blockIdx.x * 32, tr = blockIdx.y * 32;
#pragma unroll
  for (int i = 0; i < 4; i++)
    tile[ly + i * 8][lx] = in[(size_t)(tr + ly + i * 8) * C + tc + lx];
  __syncthreads();
#pragma unroll
  for (int i = 0; i < 4; i++)
    out[(size_t)(tc + ly + i * 8) * R + tr + lx] = (bf16)tile[lx][ly + i * 8];
}

// ---------------- rmsnorm (+optional roll) -> bf16 ----------------
__global__ __launch_bounds__(256) void k_rmsnorm(const float* __restrict__ x,
                                                 const float* __restrict__ g,
                                                 bf16* __restrict__ out, int shift) {
  int row = blockIdx.x;
  int b = row >> 13, r = row & (S_LEN - 1);
  int src = (b << 13) | ((r + shift) & (S_LEN - 1));
  int t = threadIdx.x;
  float4 v = *(const float4*)(x + (size_t)src * D_DIM + t * 4);
  float ss = v.x * v.x + v.y * v.y + v.z * v.z + v.w * v.w;
#pragma unroll
  for (int off = 32; off; off >>= 1) ss += __shfl_xor(ss, off);
  __shared__ float red[4];
  if ((t & 63) == 0) red[t >> 6] = ss;
  __syncthreads();
  ss = red[0] + red[1] + red[2] + red[3];
  float sc = rsqrtf(ss * (1.0f / D_DIM) + 1e-6f);
  float4 gv = *(const float4*)(g + t * 4);
  bf16x4 o;
  o[0] = (bf16)(v.x * gv.x * sc);
  o[1] = (bf16)(v.y * gv.y * sc);
  o[2] = (bf16)(v.z * gv.z * sc);
  o[3] = (bf16)(v.w * gv.w * sc);
  *(bf16x4*)(out + (size_t)row * D_DIM + t * 4) = o;
}

// ---------------- GEMM: C[M,N] = A[M,K] * BT[N,K]^T ----------------
// R11 = R7's faithful 8-phase / 2-K-tile skeleton (verified correct) +
// R3's chunk-XOR bank swizzle (verified 0-conflict on this plane layout).
// 256x256 tile, BK=64, 8 waves (2M x 4N), 512 threads, 128 KiB dynamic LDS.
// Plane: row*64B + chunk*16B; LDS chunk c holds global chunk c ^ ((row>>1)&3)
// (pre-swizzled per-lane global source; dest linear). Read chunk = lg ^ ((lr>>1)&3).
// Phase = { ds_read frags ; stage 1 half-tile ; BAR ; MFMA x16 ; BAR }.
// vmcnt(4) at phases 4 & 8 only; vmcnt(0) only at the tail.
#define VM4 asm volatile("s_waitcnt vmcnt(4)" ::: "memory")
#define VM0 asm volatile("s_waitcnt vmcnt(0)" ::: "memory")
#define BAR __builtin_amdgcn_s_barrier()

// stage half-tile: matrix (isB), K-half kc, K-tile t -> buf (t&1)
#define STAGE_H(isB, kc, t)                                               \
  {                                                                       \
    const bf16* _g = ((isB) ? gBs : gAs) + (size_t)(t) * 64 + (kc) * 32;  \
    char* _lb = smem + ((t) & 1) * 65536 + (isB) * 32768 + (kc) * 16384 + tid * 16; \
    load_lds16(_g, _lb);                                                  \
    load_lds16(_g + 128 * (size_t)K, _lb + 8192);                         \
  }

#define LDA(dst, mq, kc, bufb)                                            \
  {                                                                       \
    _Pragma("unroll") for (int mf = 0; mf < 4; mf++)                      \
        dst[mf] = *(const bf16x8*)(smem + (bufb) + (kc) * 16384 + aOff + (mq) * 4096 + mf * 1024); \
  }
#define LDB(dst, kc, bufb)                                                \
  {                                                                       \
    _Pragma("unroll") for (int nf = 0; nf < 4; nf++)                      \
        dst[nf] = *(const bf16x8*)(smem + (bufb) + (kc) * 16384 + bOff + nf * 1024); \
  }
#define MFMA16(mq, A_, B_)                                                \
  {                                                                       \
    __builtin_amdgcn_s_setprio(1);                                        \
    _Pragma("unroll") for (int mf = 0; mf < 4; mf++)                      \
        _Pragma("unroll") for (int nf = 0; nf < 4; nf++)                  \
            acc[(mq) * 4 + mf][nf] = __builtin_amdgcn_mfma_f32_16x16x32_bf16( \
                A_[mf], B_[nf], acc[(mq) * 4 + mf][nf], 0, 0, 0);         \
    __builtin_amdgcn_s_setprio(0);                                        \
  }

template <int EPI>
__global__ __launch_bounds__(512, 2) void k_gemm(const bf16* __restrict__ A,
                                                 const bf16* __restrict__ BT,
                                                 bf16* __restrict__ obf,
                                                 float* __restrict__ of32,
                                                 const float* __restrict__ bias,
                                                 const float* __restrict__ skip,
                                                 int K, int ldc) {
  extern __shared__ char smem[];  // 131072 B
  const int tid = threadIdx.x;
  const int wv = tid >> 6, lane = tid & 63;
  const int lr = lane & 15, lg = lane >> 4;
  const int wm = wv >> 2, wn = wv & 3;  // 2M x 4N waves

  // 2D-rect XCD mapping: grid = 64 * NB (1-D); XCD = bid&7 owns 16 x NB/2 rect
  const int NB = gridDim.x >> 6;
  const int xcd = blockIdx.x & 7;
  const int l = blockIdx.x >> 3;
  const int mb = ((xcd & 3) << 4) + (l & 15);
  const int nb = (xcd >> 2) * (NB >> 1) + (l >> 4);
  const int m0 = mb * 256, n0 = nb * 256;

  // staging source (per-lane, PRE-SWIZZLED): row tid>>2; LDS chunk c=tid&3
  // receives global chunk c ^ ((row>>1)&3) = c ^ ((tid>>3)&3)  [R3-verified]
  const bf16* gAs = A + (size_t)(m0 + (tid >> 2)) * K + ((tid & 3) ^ ((tid >> 3) & 3)) * 8;
  const bf16* gBs = BT + (size_t)(n0 + (tid >> 2)) * K + ((tid & 3) ^ ((tid >> 3) & 3)) * 8;

  // read-side bases within a plane (chunk-XOR key (lr>>1)&3, lane-constant)
  const int kchunk = (lg ^ ((lr >> 1) & 3)) << 4;
  const int aOff = (wm * 128 + lr) * 64 + kchunk;
  const int bOff = 32768 + (wn * 64 + lr) * 64 + kchunk;

  f32x4 acc[8][4] = {};
  const int nt = K >> 6;
  const int niter = nt >> 1;

  bf16x8 a0[4], a1[4], b0[4], b1[4];

  // prologue: t0 fully + t1.kc0 (6 half-tiles, 12 loads)
  STAGE_H(0, 0, 0);
  STAGE_H(1, 0, 0);
  STAGE_H(0, 1, 0);
  STAGE_H(1, 1, 0);
  STAGE_H(0, 0, 1);
  STAGE_H(1, 0, 1);
  VM4;  // t0 all landed; {t1.Akc0, t1.Bkc0} may be in flight
  BAR;

  for (int j = 0; j < niter; ++j) {
    const int t1 = 2 * j + 1, t2 = 2 * j + 2, t3 = 2 * j + 3;
    // ======== K-tile t0 = 2j (buf 0) ========
    // ph1: (mq0, kc0)
    LDA(a0, 0, 0, 0);
    LDB(b0, 0, 0);
    STAGE_H(0, 1, t1);  // t1.A.kc1 -> buf1 (dead since prev ph7/8)
    BAR;
    MFMA16(0, a0, b0);
    BAR;
    // ph2: (mq1, kc0)
    LDA(a1, 1, 0, 0);
    STAGE_H(1, 1, t1);  // t1.B.kc1
    BAR;
    MFMA16(1, a1, b0);
    BAR;
    // ph3: (mq1, kc1)
    LDA(a0, 1, 1, 0);
    LDB(b1, 1, 0);
    if (t2 < nt) STAGE_H(0, 0, t2);  // t2.A.kc0 -> buf0.A.kc0 (dead after ph2)
    BAR;
    MFMA16(1, a0, b1);
    BAR;
    // ph4: (mq0, kc1)
    LDA(a1, 0, 1, 0);
    if (t2 < nt) {
      STAGE_H(1, 0, t2);  // t2.B.kc0 (dead after ph1)
      VM4;                // t1 fully landed (its loads >=2 phases old)
    } else {
      VM0;                // tail: drain everything
    }
    BAR;
    MFMA16(0, a1, b1);
    BAR;
    // ======== K-tile t1 = 2j+1 (buf 65536) ========
    // ph5: (mq0, kc0)
    LDA(a0, 0, 0, 65536);
    LDB(b0, 0, 65536);
    if (t2 < nt) STAGE_H(0, 1, t2);  // t2.A.kc1 -> buf0.A.kc1 (dead after ph4)
    BAR;
    MFMA16(0, a0, b0);
    BAR;
    // ph6: (mq1, kc0)
    LDA(a1, 1, 0, 65536);
    if (t2 < nt) STAGE_H(1, 1, t2);  // t2.B.kc1 (dead after ph3)
    BAR;
    MFMA16(1, a1, b0);
    BAR;
    // ph7: (mq1, kc1)
    LDA(a0, 1, 1, 65536);
    LDB(b1, 1, 65536);
    if (t3 < nt) STAGE_H(0, 0, t3);  // t3.A.kc0 -> buf1.A.kc0 (dead after ph6)
    BAR;
    MFMA16(1, a0, b1);
    BAR;
    // ph8: (mq0, kc1)
    LDA(a1, 0, 1, 65536);
    if (t3 < nt) {
      STAGE_H(1, 0, t3);  // t3.B.kc0 (dead after ph5)
      VM4;                // t2 fully landed
    }
    BAR;
    MFMA16(0, a1, b1);
    BAR;
  }

  // ---------------- epilogue: LDS transpose, vectorized I/O ----------------
  float* lds_f = (float*)smem;
  const int erow = tid >> 3;        // 0..63
  const int ecol0 = (tid & 7) * 4;  // 0,4,..,28
#pragma unroll
  for (int mh = 0; mh < 2; mh++)
#pragma unroll
    for (int wmr = 0; wmr < 2; wmr++) {
      __syncthreads();  // prior round's reads (or K-loop) done
      if (wm == wmr) {
#pragma unroll
        for (int mf = 0; mf < 4; mf++) {
          int lrow = mf * 16 + lg * 4;
#pragma unroll
          for (int nf = 0; nf < 4; nf++) {
            int lcol = wn * 64 + nf * 16 + lr;
#pragma unroll
            for (int ii = 0; ii < 4; ii++)
              lds_f[(lrow + ii) * 260 + lcol] = acc[mh * 4 + mf][nf][ii];
          }
        }
      }
      __syncthreads();
      int gr = m0 + wmr * 128 + mh * 64 + erow;  // global row
      size_t orow;
      if constexpr (EPI == 1) {
        int b = gr >> 13, rr = gr & (S_LEN - 1);
        orow = (size_t)((b << 13) | ((rr - SHIFT_W) & (S_LEN - 1))) * ldc;
      } else {
        orow = (size_t)gr * ldc;
      }
#pragma unroll
      for (int j = 0; j < 8; j++) {
        f32x4 v = *(const f32x4*)&lds_f[erow * 260 + ecol0 + j * 32];
        int col = n0 + ecol0 + j * 32;
        if constexpr (EPI == 0) {
          bf16x4 o;
#pragma unroll
          for (int e = 0; e < 4; e++) o[e] = (bf16)v[e];
          *(bf16x4*)(obf + orow + col) = o;
        } else if constexpr (EPI == 1) {
          f32x4 s = *(const f32x4*)(skip + orow + col);
          f32x4 r = v + s;
          *(f32x4*)(of32 + orow + col) = r;
        } else if constexpr (EPI == 2) {
          f32x4 bi = *(const f32x4*)(bias + col);
          bf16x4 o;
#pragma unroll
          for (int e = 0; e < 4; e++) {
            float z = v[e] + bi[e];
            float u = 0.7978845608f * (z + 0.044715f * z * z * z);
            u = fminf(fmaxf(u, -15.f), 15.f);
            float ex = __expf(2.f * u);
            o[e] = (bf16)(0.5f * z * (1.f + (ex - 1.f) / (ex + 1.f)));
          }
          *(bf16x4*)(obf + orow + col) = o;
        } else {
          f32x4 bi = *(const f32x4*)(bias + col);
          f32x4 s = *(const f32x4*)(skip + orow + col);
          f32x4 r = v + bi + s;
          *(f32x4*)(of32 + orow + col) = r;
        }
      }
    }
}

// ---------------- windowed flash attention ----------------
__global__ __launch_bounds__(256) void k_attn(const bf16* __restrict__ qkv,
                                              bf16* __restrict__ out) {
  __shared__ __align__(16) char Qs[8192];
  __shared__ __align__(16) char Ks[8192];
  __shared__ __align__(16) char Vs[8192];
  __shared__ __align__(16) char Ps[4][2048];
  const int tid = threadIdx.x;
  const int wave = tid >> 6, lane = tid & 63;
  const int lr = lane & 15, lg = lane >> 4;
  const int bid = xcd_swizzle(blockIdx.x, gridDim.x);
  const int qt = bid & 7;
  const int h = (bid >> 3) & 15;
  const int bw = bid >> 7;
  const int rowbase = bw * 512;
  const int qrow0 = rowbase + qt * 64;

  {  // stage Q
    int r = tid >> 2, c0 = tid & 3;
    const bf16* src = qkv + (size_t)(qrow0 + r) * 3072 + h * 64;
#pragma unroll
    for (int j = 0; j < 2; j++) {
      int ch = c0 + j * 4;
      uint4 val = *(const uint4*)(src + ch * 8);
      int byte = (r * 128 + ch * 16) ^ ((r & 7) << 4);
      *(uint4*)(Qs + byte) = val;
    }
  }
  __syncthreads();
  bf16x8 qf[2];
  {
    int qr = wave * 16 + lr;
#pragma unroll
    for (int kk = 0; kk < 2; kk++) {
      int byte = (qr * 128 + (kk * 32 + lg * 8) * 2) ^ ((qr & 7) << 4);
      qf[kk] = *(const bf16x8*)(Qs + byte);
    }
  }

  f32x4 oacc[4] = {};
  float m_run = -__builtin_inff(), l_run = 0.f;

  for (int kt = 0; kt < 8; ++kt) {
    __syncthreads();
    {  // stage K and V^T
      int r = tid >> 2, c0 = tid & 3;
      const bf16* ksrc = qkv + (size_t)(rowbase + kt * 64 + r) * 3072 + 1024 + h * 64;
      const bf16* vsrc = ksrc + 1024;
#pragma unroll
      for (int j = 0; j < 2; j++) {
        int ch = c0 + j * 4;
        uint4 val = *(const uint4*)(ksrc + ch * 8);
        int byte = (r * 128 + ch * 16) ^ ((r & 7) << 4);
        *(uint4*)(Ks + byte) = val;
      }
#pragma unroll
      for (int j = 0; j < 2; j++) {
        int ch = c0 + j * 4;
        bf16x8 vv = *(const bf16x8*)(vsrc + ch * 8);
#pragma unroll
        for (int e = 0; e < 8; e++) {
          int d = ch * 8 + e;
          int byte = (d * 128 + r * 2) ^ ((d & 7) << 4);
          *(bf16*)(Vs + byte) = vv[e];
        }
      }
    }
    __syncthreads();
    f32x4 sc[4] = {};
#pragma unroll
    for (int kk = 0; kk < 2; kk++)
#pragma unroll
      for (int mf = 0; mf < 4; mf++) {
        int kr = mf * 16 + lr;
        int byte = (kr * 128 + (kk * 32 + lg * 8) * 2) ^ ((kr & 7) << 4);
        bf16x8 kf = *(const bf16x8*)(Ks + byte);
        sc[mf] = __builtin_amdgcn_mfma_f32_16x16x32_bf16(kf, qf[kk], sc[mf], 0, 0, 0);
      }
    float mx = -__builtin_inff();
#pragma unroll
    for (int mf = 0; mf < 4; mf++)
#pragma unroll
      for (int i = 0; i < 4; i++) mx = fmaxf(mx, sc[mf][i]);
    mx = fmaxf(mx, __shfl_xor(mx, 16));
    mx = fmaxf(mx, __shfl_xor(mx, 32));
    float mnew = fmaxf(m_run, mx);
    float alpha = __expf(0.125f * (m_run - mnew));
    float lsum = 0.f;
    float ps[4][4];
#pragma unroll
    for (int mf = 0; mf < 4; mf++)
#pragma unroll
      for (int i = 0; i < 4; i++) {
        float p = __expf(0.125f * (sc[mf][i] - mnew));
        ps[mf][i] = p;
        lsum += p;
      }
    lsum += __shfl_xor(lsum, 16);
    lsum += __shfl_xor(lsum, 32);
    l_run = l_run * alpha + lsum;
    m_run = mnew;
#pragma unroll
    for (int dm = 0; dm < 4; dm++) oacc[dm] *= alpha;
#pragma unroll
    for (int mf = 0; mf < 4; mf++) {
      bf16x4 pv;
#pragma unroll
      for (int i = 0; i < 4; i++) pv[i] = (bf16)ps[mf][i];
      int byte = (lr * 128 + (mf * 16 + lg * 4) * 2) ^ ((lr & 7) << 4);
      *(bf16x4*)(Ps[wave] + byte) = pv;
    }
#pragma unroll
    for (int kk = 0; kk < 2; kk++) {
      int pbyte = (lr * 128 + (kk * 32 + lg * 8) * 2) ^ ((lr & 7) << 4);
      bf16x8 pf = *(const bf16x8*)(Ps[wave] + pbyte);
#pragma unroll
      for (int dm = 0; dm < 4; dm++) {
        int d = dm * 16 + lr;
        int byte = (d * 128 + (kk * 32 + lg * 8) * 2) ^ ((d & 7) << 4);
        bf16x8 vf = *(const bf16x8*)(Vs + byte);
        oacc[dm] = __builtin_amdgcn_mfma_f32_16x16x32_bf16(vf, pf, oacc[dm], 0, 0, 0);
      }
    }
  }
  float inv = 1.f / l_run;
  int rowq = qrow0 + wave * 16 + lr;
#pragma unroll
  for (int dm = 0; dm < 4; dm++) {
    bf16x4 ov;
#pragma unroll
    for (int i = 0; i < 4; i++) ov[i] = (bf16)(oacc[dm][i] * inv);
    *(bf16x4*)(out + (size_t)rowq * 1024 + h * 64 + dm * 16 + lg * 4) = ov;
  }
}

// ---------------- launcher ----------------
extern "C" void kernel_launch(void* const* d_in, const int* in_sizes, int n_in,
                              void* d_out, int out_size, void* d_ws, size_t ws_size,
                              hipStream_t stream) {
  const float* x = (const float*)d_in[0];
  const float* wq = (const float*)d_in[1];
  const float* wk = (const float*)d_in[2];
  const float* wv = (const float*)d_in[3];
  const float* wo = (const float*)d_in[4];
  const float* ga = (const float*)d_in[5];
  const float* gf = (const float*)d_in[6];
  const float* w1 = (const float*)d_in[7];
  const float* b1 = (const float*)d_in[8];
  const float* w2 = (const float*)d_in[9];
  const float* b2 = (const float*)d_in[10];
  float* out = (float*)d_out;

  char* ws = (char*)d_ws;
  const size_t MB = 1024 * 1024;
  bf16* wqkvT = (bf16*)(ws);            // [3072][1024] bf16, 6MB
  bf16* woT = (bf16*)(ws + 6 * MB);     // [1024][1024], 2MB
  bf16* w1T = (bf16*)(ws + 8 * MB);     // [4096][1024], 8MB
  bf16* w2T = (bf16*)(ws + 16 * MB);    // [1024][4096], 8MB
  float* x1 = (float*)(ws + 24 * MB);   // [16384][1024] f32, 64MB
  bf16* hbuf = (bf16*)(ws + 88 * MB);   // 32MB: h -> attn_out -> h2
  bf16* qkv = (bf16*)(ws + 120 * MB);   // 96MB [16384][3072]; mid overlays
  bf16* mid = qkv;

  (void)hipFuncSetAttribute(reinterpret_cast<const void*>(&k_gemm<0>),
                            hipFuncAttributeMaxDynamicSharedMemorySize, 131072);
  (void)hipFuncSetAttribute(reinterpret_cast<const void*>(&k_gemm<1>),
                            hipFuncAttributeMaxDynamicSharedMemorySize, 131072);
  (void)hipFuncSetAttribute(reinterpret_cast<const void*>(&k_gemm<2>),
                            hipFuncAttributeMaxDynamicSharedMemorySize, 131072);
  (void)hipFuncSetAttribute(reinterpret_cast<const void*>(&k_gemm<3>),
                            hipFuncAttributeMaxDynamicSharedMemorySize, 131072);

  k_transpose_cvt<<<dim3(32, 32), 256, 0, stream>>>(wq, wqkvT, 1024, 1024);
  k_transpose_cvt<<<dim3(32, 32), 256, 0, stream>>>(wk, wqkvT + 1024 * 1024, 1024, 1024);
  k_transpose_cvt<<<dim3(32, 32), 256, 0, stream>>>(wv, wqkvT + 2 * 1024 * 1024, 1024, 1024);
  k_transpose_cvt<<<dim3(32, 32), 256, 0, stream>>>(wo, woT, 1024, 1024);
  k_transpose_cvt<<<dim3(128, 32), 256, 0, stream>>>(w1, w1T, 1024, 4096);
  k_transpose_cvt<<<dim3(32, 128), 256, 0, stream>>>(w2, w2T, 4096, 1024);

  // h = roll(rmsnorm(x, g_attn), -SHIFT)
  k_rmsnorm<<<NROWS, 256, 0, stream>>>(x, ga, hbuf, SHIFT_W);
  // qkv = h @ [wq|wk|wv]   (64 mb x 12 nb)
  k_gemm<0><<<64 * 12, 512, 131072, stream>>>(hbuf, wqkvT, qkv, nullptr, nullptr, nullptr, 1024, 3072);
  // windowed attention
  k_attn<<<4096, 256, 0, stream>>>(qkv, hbuf);
  // x1 = roll(attn @ wo, -SHIFT) + x   (64 x 4)
  k_gemm<1><<<64 * 4, 512, 131072, stream>>>(hbuf, woT, nullptr, x1, nullptr, x, 1024, 1024);
  // h2 = rmsnorm(x1, g_ff)
  k_rmsnorm<<<NROWS, 256, 0, stream>>>(x1, gf, hbuf, 0);
  // mid = gelu(h2 @ w1 + b1)   (64 x 16)
  k_gemm<2><<<64 * 16, 512, 131072, stream>>>(hbuf, w1T, mid, nullptr, b1, nullptr, 1024, 4096);
  // out = mid @ w2 + b2 + x1   (64 x 4, K=4096)
  k_gemm<3><<<64 * 4, 512, 131072, stream>>>(mid, w2T, nullptr, out, b2, x1, 4096, 1024);
}

// Round 12
// 612.939 us; speedup vs baseline: 1.1174x; 1.0407x over previous
//
#include <hip/hip_runtime.h>
#include <stdint.h>

#define S_LEN 8192
#define D_DIM 1024
#define SHIFT_W 256
#define NROWS 16384 /* B*S */

typedef __bf16 bf16;
typedef __bf16 bf16x8 __attribute__((ext_vector_type(8)));
typedef __bf16 bf16x4 __attribute__((ext_vector_type(4)));
typedef float f32x4 __attribute__((ext_vector_type(4)));

typedef __attribute__((address_space(1))) const void gas_t;
typedef __attribute__((address_space(3))) void las_t;

__device__ __forceinline__ void load_lds16(const void* g, void* l) {
  __builtin_amdgcn_global_load_lds((gas_t*)g, (las_t*)l, 16, 0, 0);
}

// bijective XCD remap (m204); nwg %8==0
__device__ __forceinline__ int xcd_swizzle(int orig, int nwg) {
  return (orig & 7) * (nwg >> 3) + (orig >> 3);
}

// ---------------- weight transpose + f32->bf16 ----------------
__global__ __launch_bounds__(256) void k_transpose_cvt(const float* __restrict__ in,
                                                       bf16* __restrict__ out,
                                                       int R, int C) {
  __shared__ float tile[32][33];
  int lx = threadIdx.x & 31, ly = threadIdx.x >> 5;
  int tc = blockIdx.x * 32, tr = blockIdx.y * 32;
#pragma unroll
  for (int i = 0; i < 4; i++)
    tile[ly + i * 8][lx] = in[(size_t)(tr + ly + i * 8) * C + tc + lx];
  __syncthreads();
#pragma unroll
  for (int i = 0; i < 4; i++)
    out[(size_t)(tc + ly + i * 8) * R + tr + lx] = (bf16)tile[lx][ly + i * 8];
}

// fused 4x 1024x1024 transpose (z selects matrix)
struct TP4 {
  const float* src[4];
  bf16* dst[4];
};
__global__ __launch_bounds__(256) void k_transpose4(TP4 p) {
  __shared__ float tile[32][33];
  const float* in = p.src[blockIdx.z];
  bf16* out = p.dst[blockIdx.z];
  int lx = threadIdx.x & 31, ly = threadIdx.x >> 5;
  int tc = blockIdx.x * 32, tr = blockIdx.y * 32;
#pragma unroll
  for (int i = 0; i < 4; i++)
    tile[ly + i * 8][lx] = in[(size_t)(tr + ly + i * 8) * 1024 + tc + lx];
  __syncthreads();
#pragma unroll
  for (int i = 0; i < 4; i++)
    out[(size_t)(tc + ly + i * 8) * 1024 + tr + lx] = (bf16)tile[lx][ly + i * 8];
}

// ---------------- rmsnorm (+optional roll) -> bf16, f32 input ----------------
__global__ __launch_bounds__(256) void k_rmsnorm(const float* __restrict__ x,
                                                 const float* __restrict__ g,
                                                 bf16* __restrict__ out, int shift) {
  int row = blockIdx.x;
  int b = row >> 13, r = row & (S_LEN - 1);
  int src = (b << 13) | ((r + shift) & (S_LEN - 1));
  int t = threadIdx.x;
  float4 v = *(const float4*)(x + (size_t)src * D_DIM + t * 4);
  float ss = v.x * v.x + v.y * v.y + v.z * v.z + v.w * v.w;
#pragma unroll
  for (int off = 32; off; off >>= 1) ss += __shfl_xor(ss, off);
  __shared__ float red[4];
  if ((t & 63) == 0) red[t >> 6] = ss;
  __syncthreads();
  ss = red[0] + red[1] + red[2] + red[3];
  float sc = rsqrtf(ss * (1.0f / D_DIM) + 1e-6f);
  float4 gv = *(const float4*)(g + t * 4);
  bf16x4 o;
  o[0] = (bf16)(v.x * gv.x * sc);
  o[1] = (bf16)(v.y * gv.y * sc);
  o[2] = (bf16)(v.z * gv.z * sc);
  o[3] = (bf16)(v.w * gv.w * sc);
  *(bf16x4*)(out + (size_t)row * D_DIM + t * 4) = o;
}

// rmsnorm with bf16 input (residual stream)
__global__ __launch_bounds__(256) void k_rmsnorm_bf(const bf16* __restrict__ x,
                                                    const float* __restrict__ g,
                                                    bf16* __restrict__ out) {
  int row = blockIdx.x;
  int t = threadIdx.x;
  bf16x4 xv = *(const bf16x4*)(x + (size_t)row * D_DIM + t * 4);
  float v0 = (float)xv[0], v1 = (float)xv[1], v2 = (float)xv[2], v3 = (float)xv[3];
  float ss = v0 * v0 + v1 * v1 + v2 * v2 + v3 * v3;
#pragma unroll
  for (int off = 32; off; off >>= 1) ss += __shfl_xor(ss, off);
  __shared__ float red[4];
  if ((t & 63) == 0) red[t >> 6] = ss;
  __syncthreads();
  ss = red[0] + red[1] + red[2] + red[3];
  float sc = rsqrtf(ss * (1.0f / D_DIM) + 1e-6f);
  float4 gv = *(const float4*)(g + t * 4);
  bf16x4 o;
  o[0] = (bf16)(v0 * gv.x * sc);
  o[1] = (bf16)(v1 * gv.y * sc);
  o[2] = (bf16)(v2 * gv.z * sc);
  o[3] = (bf16)(v3 * gv.w * sc);
  *(bf16x4*)(out + (size_t)row * D_DIM + t * 4) = o;
}

// ---------------- GEMM: C[M,N] = A[M,K] * BT[N,K]^T ----------------
// K-loop byte-identical to R11 (best verified: 8-phase skeleton + chunk-XOR).
// EPI: 0 = bf16 store (QKV, no extras)
//      1 = O-proj: bf16(c + skipf[rolled]) -> obf (x1 residual, bf16)
//      2 = +bias, gelu -> bf16 (FFN mid)
//      3 = f32 out = c + bias + bf16 skipb (FFN2 + residual)
#define VM4 asm volatile("s_waitcnt vmcnt(4)" ::: "memory")
#define VM0 asm volatile("s_waitcnt vmcnt(0)" ::: "memory")
#define BAR __builtin_amdgcn_s_barrier()

#define STAGE_H(isB, kc, t)                                               \
  {                                                                       \
    const bf16* _g = ((isB) ? gBs : gAs) + (size_t)(t) * 64 + (kc) * 32;  \
    char* _lb = smem + ((t) & 1) * 65536 + (isB) * 32768 + (kc) * 16384 + tid * 16; \
    load_lds16(_g, _lb);                                                  \
    load_lds16(_g + 128 * (size_t)K, _lb + 8192);                         \
  }

#define LDA(dst, mq, kc, bufb)                                            \
  {                                                                       \
    _Pragma("unroll") for (int mf = 0; mf < 4; mf++)                      \
        dst[mf] = *(const bf16x8*)(smem + (bufb) + (kc) * 16384 + aOff + (mq) * 4096 + mf * 1024); \
  }
#define LDB(dst, kc, bufb)                                                \
  {                                                                       \
    _Pragma("unroll") for (int nf = 0; nf < 4; nf++)                      \
        dst[nf] = *(const bf16x8*)(smem + (bufb) + (kc) * 16384 + bOff + nf * 1024); \
  }
#define MFMA16(mq, A_, B_)                                                \
  {                                                                       \
    __builtin_amdgcn_s_setprio(1);                                        \
    _Pragma("unroll") for (int mf = 0; mf < 4; mf++)                      \
        _Pragma("unroll") for (int nf = 0; nf < 4; nf++)                  \
            acc[(mq) * 4 + mf][nf] = __builtin_amdgcn_mfma_f32_16x16x32_bf16( \
                A_[mf], B_[nf], acc[(mq) * 4 + mf][nf], 0, 0, 0);         \
    __builtin_amdgcn_s_setprio(0);                                        \
  }

template <int EPI>
__global__ __launch_bounds__(512, 2) void k_gemm(const bf16* __restrict__ A,
                                                 const bf16* __restrict__ BT,
                                                 bf16* __restrict__ obf,
                                                 float* __restrict__ of32,
                                                 const float* __restrict__ bias,
                                                 const float* __restrict__ skipf,
                                                 const bf16* __restrict__ skipb,
                                                 int K, int ldc) {
  extern __shared__ char smem[];  // 131072 B
  const int tid = threadIdx.x;
  const int wv = tid >> 6, lane = tid & 63;
  const int lr = lane & 15, lg = lane >> 4;
  const int wm = wv >> 2, wn = wv & 3;  // 2M x 4N waves

  // 2D-rect XCD mapping: grid = 64 * NB (1-D); XCD = bid&7 owns 16 x NB/2 rect
  const int NB = gridDim.x >> 6;
  const int xcd = blockIdx.x & 7;
  const int l = blockIdx.x >> 3;
  const int mb = ((xcd & 3) << 4) + (l & 15);
  const int nb = (xcd >> 2) * (NB >> 1) + (l >> 4);
  const int m0 = mb * 256, n0 = nb * 256;

  // staging source (per-lane, PRE-SWIZZLED): row tid>>2; LDS chunk c=tid&3
  // receives global chunk c ^ ((tid>>3)&3)
  const bf16* gAs = A + (size_t)(m0 + (tid >> 2)) * K + ((tid & 3) ^ ((tid >> 3) & 3)) * 8;
  const bf16* gBs = BT + (size_t)(n0 + (tid >> 2)) * K + ((tid & 3) ^ ((tid >> 3) & 3)) * 8;

  // read-side bases within a plane (chunk-XOR key (lr>>1)&3, lane-constant)
  const int kchunk = (lg ^ ((lr >> 1) & 3)) << 4;
  const int aOff = (wm * 128 + lr) * 64 + kchunk;
  const int bOff = 32768 + (wn * 64 + lr) * 64 + kchunk;

  f32x4 acc[8][4] = {};
  const int nt = K >> 6;
  const int niter = nt >> 1;

  bf16x8 a0[4], a1[4], b0[4], b1[4];

  // prologue: t0 fully + t1.kc0 (6 half-tiles, 12 loads)
  STAGE_H(0, 0, 0);
  STAGE_H(1, 0, 0);
  STAGE_H(0, 1, 0);
  STAGE_H(1, 1, 0);
  STAGE_H(0, 0, 1);
  STAGE_H(1, 0, 1);
  VM4;  // t0 all landed
  BAR;

  for (int j = 0; j < niter; ++j) {
    const int t1 = 2 * j + 1, t2 = 2 * j + 2, t3 = 2 * j + 3;
    // ph1: (mq0, kc0)
    LDA(a0, 0, 0, 0);
    LDB(b0, 0, 0);
    STAGE_H(0, 1, t1);
    BAR;
    MFMA16(0, a0, b0);
    BAR;
    // ph2: (mq1, kc0)
    LDA(a1, 1, 0, 0);
    STAGE_H(1, 1, t1);
    BAR;
    MFMA16(1, a1, b0);
    BAR;
    // ph3: (mq1, kc1)
    LDA(a0, 1, 1, 0);
    LDB(b1, 1, 0);
    if (t2 < nt) STAGE_H(0, 0, t2);
    BAR;
    MFMA16(1, a0, b1);
    BAR;
    // ph4: (mq0, kc1)
    LDA(a1, 0, 1, 0);
    if (t2 < nt) {
      STAGE_H(1, 0, t2);
      VM4;
    } else {
      VM0;
    }
    BAR;
    MFMA16(0, a1, b1);
    BAR;
    // ph5: (mq0, kc0) of t1
    LDA(a0, 0, 0, 65536);
    LDB(b0, 0, 65536);
    if (t2 < nt) STAGE_H(0, 1, t2);
    BAR;
    MFMA16(0, a0, b0);
    BAR;
    // ph6: (mq1, kc0)
    LDA(a1, 1, 0, 65536);
    if (t2 < nt) STAGE_H(1, 1, t2);
    BAR;
    MFMA16(1, a1, b0);
    BAR;
    // ph7: (mq1, kc1)
    LDA(a0, 1, 1, 65536);
    LDB(b1, 1, 65536);
    if (t3 < nt) STAGE_H(0, 0, t3);
    BAR;
    MFMA16(1, a0, b1);
    BAR;
    // ph8: (mq0, kc1)
    LDA(a1, 0, 1, 65536);
    if (t3 < nt) {
      STAGE_H(1, 0, t3);
      VM4;
    }
    BAR;
    MFMA16(0, a1, b1);
    BAR;
  }

  // ---------------- epilogue: LDS transpose, vectorized I/O ----------------
  float* lds_f = (float*)smem;
  const int erow = tid >> 3;        // 0..63
  const int ecol0 = (tid & 7) * 4;  // 0,4,..,28
#pragma unroll
  for (int mh = 0; mh < 2; mh++)
#pragma unroll
    for (int wmr = 0; wmr < 2; wmr++) {
      __syncthreads();
      if (wm == wmr) {
#pragma unroll
        for (int mf = 0; mf < 4; mf++) {
          int lrow = mf * 16 + lg * 4;
#pragma unroll
          for (int nf = 0; nf < 4; nf++) {
            int lcol = wn * 64 + nf * 16 + lr;
#pragma unroll
            for (int ii = 0; ii < 4; ii++)
              lds_f[(lrow + ii) * 260 + lcol] = acc[mh * 4 + mf][nf][ii];
          }
        }
      }
      __syncthreads();
      int gr = m0 + wmr * 128 + mh * 64 + erow;  // global row
      size_t orow;
      if constexpr (EPI == 1) {
        int b = gr >> 13, rr = gr & (S_LEN - 1);
        orow = (size_t)((b << 13) | ((rr - SHIFT_W) & (S_LEN - 1))) * ldc;
      } else {
        orow = (size_t)gr * ldc;
      }
#pragma unroll
      for (int j = 0; j < 8; j++) {
        f32x4 v = *(const f32x4*)&lds_f[erow * 260 + ecol0 + j * 32];
        int col = n0 + ecol0 + j * 32;
        if constexpr (EPI == 0) {
          bf16x4 o;
#pragma unroll
          for (int e = 0; e < 4; e++) o[e] = (bf16)v[e];
          *(bf16x4*)(obf + orow + col) = o;
        } else if constexpr (EPI == 1) {
          f32x4 s = *(const f32x4*)(skipf + orow + col);
          bf16x4 o;
#pragma unroll
          for (int e = 0; e < 4; e++) o[e] = (bf16)(v[e] + s[e]);
          *(bf16x4*)(obf + orow + col) = o;
        } else if constexpr (EPI == 2) {
          f32x4 bi = *(const f32x4*)(bias + col);
          bf16x4 o;
#pragma unroll
          for (int e = 0; e < 4; e++) {
            float z = v[e] + bi[e];
            float u = 0.7978845608f * (z + 0.044715f * z * z * z);
            u = fminf(fmaxf(u, -15.f), 15.f);
            float ex = __expf(2.f * u);
            o[e] = (bf16)(0.5f * z * (1.f + (ex - 1.f) / (ex + 1.f)));
          }
          *(bf16x4*)(obf + orow + col) = o;
        } else {
          f32x4 bi = *(const f32x4*)(bias + col);
          bf16x4 s = *(const bf16x4*)(skipb + orow + col);
          f32x4 r;
#pragma unroll
          for (int e = 0; e < 4; e++) r[e] = v[e] + bi[e] + (float)s[e];
          *(f32x4*)(of32 + orow + col) = r;
        }
      }
    }
}

// ---------------- windowed flash attention ----------------
__global__ __launch_bounds__(256) void k_attn(const bf16* __restrict__ qkv,
                                              bf16* __restrict__ out) {
  __shared__ __align__(16) char Qs[8192];
  __shared__ __align__(16) char Ks[8192];
  __shared__ __align__(16) char Vs[8192];
  __shared__ __align__(16) char Ps[4][2048];
  const int tid = threadIdx.x;
  const int wave = tid >> 6, lane = tid & 63;
  const int lr = lane & 15, lg = lane >> 4;
  const int bid = xcd_swizzle(blockIdx.x, gridDim.x);
  const int qt = bid & 7;
  const int h = (bid >> 3) & 15;
  const int bw = bid >> 7;
  const int rowbase = bw * 512;
  const int qrow0 = rowbase + qt * 64;

  {  // stage Q
    int r = tid >> 2, c0 = tid & 3;
    const bf16* src = qkv + (size_t)(qrow0 + r) * 3072 + h * 64;
#pragma unroll
    for (int j = 0; j < 2; j++) {
      int ch = c0 + j * 4;
      uint4 val = *(const uint4*)(src + ch * 8);
      int byte = (r * 128 + ch * 16) ^ ((r & 7) << 4);
      *(uint4*)(Qs + byte) = val;
    }
  }
  __syncthreads();
  bf16x8 qf[2];
  {
    int qr = wave * 16 + lr;
#pragma unroll
    for (int kk = 0; kk < 2; kk++) {
      int byte = (qr * 128 + (kk * 32 + lg * 8) * 2) ^ ((qr & 7) << 4);
      qf[kk] = *(const bf16x8*)(Qs + byte);
    }
  }

  f32x4 oacc[4] = {};
  float m_run = -__builtin_inff(), l_run = 0.f;

  for (int kt = 0; kt < 8; ++kt) {
    __syncthreads();
    {  // stage K and V^T
      int r = tid >> 2, c0 = tid & 3;
      const bf16* ksrc = qkv + (size_t)(rowbase + kt * 64 + r) * 3072 + 1024 + h * 64;
      const bf16* vsrc = ksrc + 1024;
#pragma unroll
      for (int j = 0; j < 2; j++) {
        int ch = c0 + j * 4;
        uint4 val = *(const uint4*)(ksrc + ch * 8);
        int byte = (r * 128 + ch * 16) ^ ((r & 7) << 4);
        *(uint4*)(Ks + byte) = val;
      }
#pragma unroll
      for (int j = 0; j < 2; j++) {
        int ch = c0 + j * 4;
        bf16x8 vv = *(const bf16x8*)(vsrc + ch * 8);
#pragma unroll
        for (int e = 0; e < 8; e++) {
          int d = ch * 8 + e;
          int byte = (d * 128 + r * 2) ^ ((d & 7) << 4);
          *(bf16*)(Vs + byte) = vv[e];
        }
      }
    }
    __syncthreads();
    f32x4 sc[4] = {};
#pragma unroll
    for (int kk = 0; kk < 2; kk++)
#pragma unroll
      for (int mf = 0; mf < 4; mf++) {
        int kr = mf * 16 + lr;
        int byte = (kr * 128 + (kk * 32 + lg * 8) * 2) ^ ((kr & 7) << 4);
        bf16x8 kf = *(const bf16x8*)(Ks + byte);
        sc[mf] = __builtin_amdgcn_mfma_f32_16x16x32_bf16(kf, qf[kk], sc[mf], 0, 0, 0);
      }
    float mx = -__builtin_inff();
#pragma unroll
    for (int mf = 0; mf < 4; mf++)
#pragma unroll
      for (int i = 0; i < 4; i++) mx = fmaxf(mx, sc[mf][i]);
    mx = fmaxf(mx, __shfl_xor(mx, 16));
    mx = fmaxf(mx, __shfl_xor(mx, 32));
    float mnew = fmaxf(m_run, mx);
    float alpha = __expf(0.125f * (m_run - mnew));
    float lsum = 0.f;
    float ps[4][4];
#pragma unroll
    for (int mf = 0; mf < 4; mf++)
#pragma unroll
      for (int i = 0; i < 4; i++) {
        float p = __expf(0.125f * (sc[mf][i] - mnew));
        ps[mf][i] = p;
        lsum += p;
      }
    lsum += __shfl_xor(lsum, 16);
    lsum += __shfl_xor(lsum, 32);
    l_run = l_run * alpha + lsum;
    m_run = mnew;
#pragma unroll
    for (int dm = 0; dm < 4; dm++) oacc[dm] *= alpha;
#pragma unroll
    for (int mf = 0; mf < 4; mf++) {
      bf16x4 pv;
#pragma unroll
      for (int i = 0; i < 4; i++) pv[i] = (bf16)ps[mf][i];
      int byte = (lr * 128 + (mf * 16 + lg * 4) * 2) ^ ((lr & 7) << 4);
      *(bf16x4*)(Ps[wave] + byte) = pv;
    }
#pragma unroll
    for (int kk = 0; kk < 2; kk++) {
      int pbyte = (lr * 128 + (kk * 32 + lg * 8) * 2) ^ ((lr & 7) << 4);
      bf16x8 pf = *(const bf16x8*)(Ps[wave] + pbyte);
#pragma unroll
      for (int dm = 0; dm < 4; dm++) {
        int d = dm * 16 + lr;
        int byte = (d * 128 + (kk * 32 + lg * 8) * 2) ^ ((d & 7) << 4);
        bf16x8 vf = *(const bf16x8*)(Vs + byte);
        oacc[dm] = __builtin_amdgcn_mfma_f32_16x16x32_bf16(vf, pf, oacc[dm], 0, 0, 0);
      }
    }
  }
  float inv = 1.f / l_run;
  int rowq = qrow0 + wave * 16 + lr;
#pragma unroll
  for (int dm = 0; dm < 4; dm++) {
    bf16x4 ov;
#pragma unroll
    for (int i = 0; i < 4; i++) ov[i] = (bf16)(oacc[dm][i] * inv);
    *(bf16x4*)(out + (size_t)rowq * 1024 + h * 64 + dm * 16 + lg * 4) = ov;
  }
}

// ---------------- launcher ----------------
extern "C" void kernel_launch(void* const* d_in, const int* in_sizes, int n_in,
                              void* d_out, int out_size, void* d_ws, size_t ws_size,
                              hipStream_t stream) {
  const float* x = (const float*)d_in[0];
  const float* wq = (const float*)d_in[1];
  const float* wk = (const float*)d_in[2];
  const float* wv = (const float*)d_in[3];
  const float* wo = (const float*)d_in[4];
  const float* ga = (const float*)d_in[5];
  const float* gf = (const float*)d_in[6];
  const float* w1 = (const float*)d_in[7];
  const float* b1 = (const float*)d_in[8];
  const float* w2 = (const float*)d_in[9];
  const float* b2 = (const float*)d_in[10];
  float* out = (float*)d_out;

  char* ws = (char*)d_ws;
  const size_t MB = 1024 * 1024;
  bf16* wqkvT = (bf16*)(ws);            // [3072][1024] bf16, 6MB
  bf16* woT = (bf16*)(ws + 6 * MB);     // [1024][1024], 2MB
  bf16* w1T = (bf16*)(ws + 8 * MB);     // [4096][1024], 8MB
  bf16* w2T = (bf16*)(ws + 16 * MB);    // [1024][4096], 8MB
  bf16* x1b = (bf16*)(ws + 24 * MB);    // [16384][1024] bf16, 32MB (residual)
  bf16* hbuf = (bf16*)(ws + 88 * MB);   // 32MB: h -> attn_out -> h2
  bf16* qkv = (bf16*)(ws + 120 * MB);   // 96MB [16384][3072]; mid overlays
  bf16* mid = qkv;

  (void)hipFuncSetAttribute(reinterpret_cast<const void*>(&k_gemm<0>),
                            hipFuncAttributeMaxDynamicSharedMemorySize, 131072);
  (void)hipFuncSetAttribute(reinterpret_cast<const void*>(&k_gemm<1>),
                            hipFuncAttributeMaxDynamicSharedMemorySize, 131072);
  (void)hipFuncSetAttribute(reinterpret_cast<const void*>(&k_gemm<2>),
                            hipFuncAttributeMaxDynamicSharedMemorySize, 131072);
  (void)hipFuncSetAttribute(reinterpret_cast<const void*>(&k_gemm<3>),
                            hipFuncAttributeMaxDynamicSharedMemorySize, 131072);

  TP4 tp;
  tp.src[0] = wq;  tp.dst[0] = wqkvT;
  tp.src[1] = wk;  tp.dst[1] = wqkvT + 1024 * 1024;
  tp.src[2] = wv;  tp.dst[2] = wqkvT + 2 * 1024 * 1024;
  tp.src[3] = wo;  tp.dst[3] = woT;
  k_transpose4<<<dim3(32, 32, 4), 256, 0, stream>>>(tp);
  k_transpose_cvt<<<dim3(128, 32), 256, 0, stream>>>(w1, w1T, 1024, 4096);
  k_transpose_cvt<<<dim3(32, 128), 256, 0, stream>>>(w2, w2T, 4096, 1024);

  // h = roll(rmsnorm(x, g_attn), -SHIFT)
  k_rmsnorm<<<NROWS, 256, 0, stream>>>(x, ga, hbuf, SHIFT_W);
  // qkv = h @ [wq|wk|wv]   (64 mb x 12 nb)
  k_gemm<0><<<64 * 12, 512, 131072, stream>>>(hbuf, wqkvT, qkv, nullptr, nullptr, nullptr, nullptr, 1024, 3072);
  // windowed attention
  k_attn<<<4096, 256, 0, stream>>>(qkv, hbuf);
  // x1 = bf16( roll(attn @ wo, -SHIFT) + x )   (64 x 4)
  k_gemm<1><<<64 * 4, 512, 131072, stream>>>(hbuf, woT, x1b, nullptr, nullptr, x, nullptr, 1024, 1024);
  // h2 = rmsnorm(x1, g_ff)
  k_rmsnorm_bf<<<NROWS, 256, 0, stream>>>(x1b, gf, hbuf);
  // mid = gelu(h2 @ w1 + b1)   (64 x 16)
  k_gemm<2><<<64 * 16, 512, 131072, stream>>>(hbuf, w1T, mid, nullptr, b1, nullptr, nullptr, 1024, 4096);
  // out = mid @ w2 + b2 + x1   (64 x 4, K=4096)
  k_gemm<3><<<64 * 4, 512, 131072, stream>>>(mid, w2T, nullptr, out, b2, nullptr, x1b, 4096, 1024);
}